// Round 6
// baseline (112.044 us; speedup 1.0000x reference)
//
#include <hip/hip_runtime.h>

// ---------------- static config (matches reference) ----------------
// Fine byte grid only: 2048 x 2048 x 1B = 4 MB. Coarser grids (1024^2,
// 512^2) are derived in the reduce: coarse cell = OR of 2x2 / 4x4 fine
// cells. Reciprocal-multiply instead of fp divide shifts floor() only for
// boundary-adjacent points (O(few) of 8M, +-1 per slice count; threshold
// 1121, measured absmax 0 through round 5).
//
// Scatter decouples the two cache constraints found in rounds 4/5:
//  - FETCH: only 2 block-groups share each point chunk (round 5 proved
//    2-way sharing gives compulsory-only HBM fetch; 4-way refetched 50%).
//  - WRITE: each block covers its 1024-row region in TWO temporal
//    sub-phases of 512 rows (512 KB hot per XCD L2; round 4 proved ~1 MB
//    stays clean vs the nt point stream, round 5 proved 2 MB thrashes).
//    Sub-phase 2 re-reads the block's own contiguous 64 KB point range
//    from L3 (points are L3-resident after pass 1).
static constexpr int GF = 2048;                      // fine grid dim
static constexpr int V4PR = GF / 16;                 // 128 uint4 per fine row
static constexpr size_t GRID_BYTES = (size_t)GF * GF;   // 4 MiB

typedef float f32x4 __attribute__((ext_vector_type(4)));

// ---------------- scatter: 2 groups x 2 sub-phases, idempotent byte stores ----
__global__ void __launch_bounds__(256)
mpc_scatter_sub(const f32x4* __restrict__ pts4, int npairs,
                const float* __restrict__ psz,   // [3][2]
                const float* __restrict__ pmin,  // [2]
                unsigned char* __restrict__ grid) {
    const float minx = pmin[0], miny = pmin[1];
    const float rx = 1.0f / psz[0], ry = 1.0f / psz[1];

    const int region = blockIdx.x & 1;       // row-half: even XCDs 0..1023, odd 1024..2047
    const int gblk   = blockIdx.x >> 1;
    const int ngrp   = gridDim.x >> 1;
    const int per    = (npairs + ngrp - 1) / ngrp;
    const int lo     = gblk * per;
    const int hi     = min(lo + per, npairs);
    const int B      = blockDim.x;

    auto process = [&](const f32x4& q, int band) {
#pragma unroll
        for (int k = 0; k < 2; ++k) {
            const float py = (k == 0 ? q.y : q.w) - miny;
            int cy = __float2int_rd(py * ry);
            cy = min(max(cy, 0), GF - 1);
            if ((cy >> 9) == band) {                       // 512-row band
                const float px = (k == 0 ? q.x : q.z) - minx;
                int cx = __float2int_rd(px * rx);
                cx = min(max(cx, 0), GF - 1);
                grid[(unsigned)cy * (unsigned)GF + (unsigned)cx] = (unsigned char)1;
            }
        }
    };

#pragma unroll
    for (int sub = 0; sub < 2; ++sub) {
        const int band = region * 2 + sub;   // cy>>9 selector for this pass
        int i = lo + (int)threadIdx.x;
        // 4-way unrolled main loop: 4 independent nt loads in flight
        for (; i + 3 * B < hi; i += 4 * B) {
            const f32x4 q0 = __builtin_nontemporal_load(&pts4[i]);
            const f32x4 q1 = __builtin_nontemporal_load(&pts4[i + B]);
            const f32x4 q2 = __builtin_nontemporal_load(&pts4[i + 2 * B]);
            const f32x4 q3 = __builtin_nontemporal_load(&pts4[i + 3 * B]);
            process(q0, band);
            process(q1, band);
            process(q2, band);
            process(q3, band);
        }
        for (; i < hi; i += B) {
            const f32x4 q = __builtin_nontemporal_load(&pts4[i]);
            process(q, band);
        }
    }
}

// ---------------- reduce: per-slice counts for all 3 resolutions ----------------
// block b in [0,112): b<64 -> res0 slice b (32 fine rows, popcount of 0/1 bytes)
//                     b<96 -> res1 slice b-64 (64 fine rows, 2x2 byte-OR)
//                     else -> res2 slice b-96 (128 fine rows, 4x4 byte-OR)
__global__ void mpc_reduce_bytes(const uint4* __restrict__ g4,
                                 float* __restrict__ out) {
    const int b = blockIdx.x;
    const int tid = threadIdx.x;
    unsigned int sum = 0;

    if (b < 64) {
        const uint4* base = g4 + (size_t)b * 32 * V4PR;
        for (int j = tid; j < 32 * V4PR; j += blockDim.x) {
            const uint4 v = base[j];
            sum += __popc(v.x) + __popc(v.y) + __popc(v.z) + __popc(v.w);
        }
    } else if (b < 96) {
        const int s = b - 64;
        const uint4* base = g4 + (size_t)s * 64 * V4PR;
        for (int j = tid; j < 32 * V4PR; j += blockDim.x) {
            const int cr = j >> 7;           // coarse row in slice
            const int v  = j & (V4PR - 1);   // vec index within row
            const uint4 r0 = base[(size_t)(2 * cr) * V4PR + v];
            const uint4 r1 = base[(size_t)(2 * cr + 1) * V4PR + v];
            unsigned o;
            o = r0.x | r1.x; o |= o >> 8; sum += __popc(o & 0x00010001u);
            o = r0.y | r1.y; o |= o >> 8; sum += __popc(o & 0x00010001u);
            o = r0.z | r1.z; o |= o >> 8; sum += __popc(o & 0x00010001u);
            o = r0.w | r1.w; o |= o >> 8; sum += __popc(o & 0x00010001u);
        }
    } else {
        const int s = b - 96;
        const uint4* base = g4 + (size_t)s * 128 * V4PR;
        for (int j = tid; j < 32 * V4PR; j += blockDim.x) {
            const int cr = j >> 7;
            const int v  = j & (V4PR - 1);
            const uint4 a = base[(size_t)(4 * cr) * V4PR + v];
            const uint4 c = base[(size_t)(4 * cr + 1) * V4PR + v];
            const uint4 d = base[(size_t)(4 * cr + 2) * V4PR + v];
            const uint4 e = base[(size_t)(4 * cr + 3) * V4PR + v];
            unsigned o;
            o = a.x | c.x | d.x | e.x; o |= o >> 16; o |= o >> 8; sum += o & 1u;
            o = a.y | c.y | d.y | e.y; o |= o >> 16; o |= o >> 8; sum += o & 1u;
            o = a.z | c.z | d.z | e.z; o |= o >> 16; o |= o >> 8; sum += o & 1u;
            o = a.w | c.w | d.w | e.w; o |= o >> 16; o |= o >> 8; sum += o & 1u;
        }
    }

#pragma unroll
    for (int o = 32; o > 0; o >>= 1) sum += __shfl_down(sum, o, 64);
    __shared__ unsigned int ssum[4];
    const int wave = tid >> 6, lane = tid & 63;
    if (lane == 0) ssum[wave] = sum;
    __syncthreads();
    if (tid == 0) {
        unsigned int t = 0;
        const int nw = blockDim.x >> 6;
        for (int w = 0; w < nw; ++w) t += ssum[w];
        out[b] = (float)t;
    }
}

extern "C" void kernel_launch(void* const* d_in, const int* in_sizes, int n_in,
                              void* d_out, int out_size, void* d_ws, size_t ws_size,
                              hipStream_t stream) {
    const f32x4* pts4 = (const f32x4*)d_in[0];
    const float* psz  = (const float*)d_in[1];
    const float* pmn  = (const float*)d_in[2];
    float* out = (float*)d_out;
    const int n = in_sizes[0] / 2;     // number of points (8M, even)
    const int npairs = n / 2;

    unsigned char* grid = (unsigned char*)d_ws;
    hipMemsetAsync(grid, 0, GRID_BYTES, stream);

    const int threads = 256;
    const int blocks = 2048;           // multiple of 8: balanced XCD spread

    mpc_scatter_sub<<<blocks, threads, 0, stream>>>(pts4, npairs, psz, pmn, grid);
    mpc_reduce_bytes<<<112, 256, 0, stream>>>((const uint4*)d_ws, out);
}

// Round 7
// 82.076 us; speedup vs baseline: 1.3651x; 1.3651x over previous
//
#include <hip/hip_runtime.h>

// ---------------- static config (matches reference) ----------------
// Fine byte grid only: 2048 x 2048 x 1B = 4 MB. Coarser grids (1024^2,
// 512^2) are derived in the reduce: coarse cell = OR of 2x2 / 4x4 fine
// cells. Reciprocal-multiply instead of fp divide shifts floor() only for
// boundary-adjacent points (O(few) of 8M, +-1 per slice count; threshold
// 1121, measured absmax 0 rounds 1-6).
//
// Scatter: NREG=4 region passes (1 MB hot region per XCD -> clean writes,
// round 4: 8.6 MB writeback) with CACHED point loads (round 6 proved
// nontemporal loads are not retained in L3: a block's own just-read range
// re-fetched from HBM). The 64 MB point array fits the 256 MB L3, so
// passes 2-4 should be L3 hits. Tripwires: WRITE >> 30 MB -> L2 needs nt
// protection; FETCH >= 125 MB -> L3 retention wrong -> go to binning.
static constexpr int GF = 2048;                      // fine grid dim
static constexpr int V4PR = GF / 16;                 // 128 uint4 per fine row
static constexpr size_t GRID_BYTES = (size_t)GF * GF;   // 4 MiB
static constexpr int NREG = 4;                       // regions (power of 2)
static constexpr int REG_SHIFT = 9;                  // 2048/4 = 512 rows/region

typedef float f32x4 __attribute__((ext_vector_type(4)));

// ---------------- scatter: region-filtered idempotent byte stores ----------------
__global__ void __launch_bounds__(256)
mpc_scatter_r4(const f32x4* __restrict__ pts4, int npairs,
               const float* __restrict__ psz,   // [3][2]
               const float* __restrict__ pmin,  // [2]
               unsigned char* __restrict__ grid) {
    const float minx = pmin[0], miny = pmin[1];
    const float rx = 1.0f / psz[0], ry = 1.0f / psz[1];

    const int region = blockIdx.x & (NREG - 1);
    const int gblk   = blockIdx.x >> 2;
    const int nblk   = gridDim.x >> 2;
    const int B      = blockDim.x;
    const int tpg    = nblk * B;                     // threads per group

    auto process = [&](const f32x4& q) {
#pragma unroll
        for (int k = 0; k < 2; ++k) {
            const float py = (k == 0 ? q.y : q.w) - miny;
            int cy = __float2int_rd(py * ry);
            cy = min(max(cy, 0), GF - 1);
            if ((cy >> REG_SHIFT) == region) {
                const float px = (k == 0 ? q.x : q.z) - minx;
                int cx = __float2int_rd(px * rx);
                cx = min(max(cx, 0), GF - 1);
                grid[(unsigned)cy * (unsigned)GF + (unsigned)cx] = (unsigned char)1;
            }
        }
    };

    int i = gblk * B + threadIdx.x;
    // 4-way unrolled: 4 independent cached loads in flight
    for (; i + 3 * tpg < npairs; i += 4 * tpg) {
        const f32x4 q0 = pts4[i];
        const f32x4 q1 = pts4[i + tpg];
        const f32x4 q2 = pts4[i + 2 * tpg];
        const f32x4 q3 = pts4[i + 3 * tpg];
        process(q0);
        process(q1);
        process(q2);
        process(q3);
    }
    for (; i < npairs; i += tpg) {
        process(pts4[i]);
    }
}

// ---------------- reduce: per-slice counts for all 3 resolutions ----------------
// block b in [0,112): b<64 -> res0 slice b (32 fine rows, popcount of 0/1 bytes)
//                     b<96 -> res1 slice b-64 (64 fine rows, 2x2 byte-OR)
//                     else -> res2 slice b-96 (128 fine rows, 4x4 byte-OR)
__global__ void mpc_reduce_bytes(const uint4* __restrict__ g4,
                                 float* __restrict__ out) {
    const int b = blockIdx.x;
    const int tid = threadIdx.x;
    unsigned int sum = 0;

    if (b < 64) {
        const uint4* base = g4 + (size_t)b * 32 * V4PR;
        for (int j = tid; j < 32 * V4PR; j += blockDim.x) {
            const uint4 v = base[j];
            sum += __popc(v.x) + __popc(v.y) + __popc(v.z) + __popc(v.w);
        }
    } else if (b < 96) {
        const int s = b - 64;
        const uint4* base = g4 + (size_t)s * 64 * V4PR;
        for (int j = tid; j < 32 * V4PR; j += blockDim.x) {
            const int cr = j >> 7;           // coarse row in slice
            const int v  = j & (V4PR - 1);   // vec index within row
            const uint4 r0 = base[(size_t)(2 * cr) * V4PR + v];
            const uint4 r1 = base[(size_t)(2 * cr + 1) * V4PR + v];
            unsigned o;
            o = r0.x | r1.x; o |= o >> 8; sum += __popc(o & 0x00010001u);
            o = r0.y | r1.y; o |= o >> 8; sum += __popc(o & 0x00010001u);
            o = r0.z | r1.z; o |= o >> 8; sum += __popc(o & 0x00010001u);
            o = r0.w | r1.w; o |= o >> 8; sum += __popc(o & 0x00010001u);
        }
    } else {
        const int s = b - 96;
        const uint4* base = g4 + (size_t)s * 128 * V4PR;
        for (int j = tid; j < 32 * V4PR; j += blockDim.x) {
            const int cr = j >> 7;
            const int v  = j & (V4PR - 1);
            const uint4 a = base[(size_t)(4 * cr) * V4PR + v];
            const uint4 c = base[(size_t)(4 * cr + 1) * V4PR + v];
            const uint4 d = base[(size_t)(4 * cr + 2) * V4PR + v];
            const uint4 e = base[(size_t)(4 * cr + 3) * V4PR + v];
            unsigned o;
            o = a.x | c.x | d.x | e.x; o |= o >> 16; o |= o >> 8; sum += o & 1u;
            o = a.y | c.y | d.y | e.y; o |= o >> 16; o |= o >> 8; sum += o & 1u;
            o = a.z | c.z | d.z | e.z; o |= o >> 16; o |= o >> 8; sum += o & 1u;
            o = a.w | c.w | d.w | e.w; o |= o >> 16; o |= o >> 8; sum += o & 1u;
        }
    }

#pragma unroll
    for (int o = 32; o > 0; o >>= 1) sum += __shfl_down(sum, o, 64);
    __shared__ unsigned int ssum[4];
    const int wave = tid >> 6, lane = tid & 63;
    if (lane == 0) ssum[wave] = sum;
    __syncthreads();
    if (tid == 0) {
        unsigned int t = 0;
        const int nw = blockDim.x >> 6;
        for (int w = 0; w < nw; ++w) t += ssum[w];
        out[b] = (float)t;
    }
}

extern "C" void kernel_launch(void* const* d_in, const int* in_sizes, int n_in,
                              void* d_out, int out_size, void* d_ws, size_t ws_size,
                              hipStream_t stream) {
    const f32x4* pts4 = (const f32x4*)d_in[0];
    const float* psz  = (const float*)d_in[1];
    const float* pmn  = (const float*)d_in[2];
    float* out = (float*)d_out;
    const int n = in_sizes[0] / 2;     // number of points (8M, even)
    const int npairs = n / 2;

    unsigned char* grid = (unsigned char*)d_ws;
    hipMemsetAsync(grid, 0, GRID_BYTES, stream);

    const int threads = 256;
    const int blocks = 2048;           // multiple of 8: balanced XCD spread

    mpc_scatter_r4<<<blocks, threads, 0, stream>>>(pts4, npairs, psz, pmn, grid);
    mpc_reduce_bytes<<<112, 256, 0, stream>>>((const uint4*)d_ws, out);
}